// Round 1
// baseline (72.753 us; speedup 1.0000x reference)
//
#include <hip/hip_runtime.h>
#include <hip/hip_bf16.h>

// Layered fully-connected chain: 15 layers of 2048x2048 matvec.
// v_{l+1} = silu(W[l] @ v_l + b[l]) for l=0..13; out = W[14] @ v_14 + b[14].
// One wave per output row, float4 loads, shuffle reduce.

#define NN 2048
#define NLAYERS 15

__global__ __launch_bounds__(256) void layer_matvec(
    const float* __restrict__ W,    // [NN, NN] row-major
    const float* __restrict__ b,    // [NN]
    const float* __restrict__ vin,  // [NN]
    float* __restrict__ vout,       // [NN]
    int apply_silu)
{
    const int lane = threadIdx.x & 63;
    const int wave_in_block = threadIdx.x >> 6;
    const int row = blockIdx.x * 4 + wave_in_block;   // 512 blocks * 4 waves

    const float4* __restrict__ Wrow =
        reinterpret_cast<const float4*>(W + (size_t)row * NN);
    const float4* __restrict__ v4 =
        reinterpret_cast<const float4*>(vin);

    float acc = 0.f;
#pragma unroll
    for (int k = 0; k < 8; ++k) {
        float4 w = Wrow[lane + k * 64];
        float4 v = v4[lane + k * 64];
        acc += w.x * v.x + w.y * v.y + w.z * v.z + w.w * v.w;
    }

    // wave-wide reduction (64 lanes)
#pragma unroll
    for (int off = 32; off > 0; off >>= 1)
        acc += __shfl_down(acc, off);

    if (lane == 0) {
        float z = acc + b[row];
        if (apply_silu) {
            // silu(z) = z * sigmoid(z)
            z = z / (1.f + expf(-z));
        }
        vout[row] = z;
    }
}

extern "C" void kernel_launch(void* const* d_in, const int* in_sizes, int n_in,
                              void* d_out, int out_size, void* d_ws, size_t ws_size,
                              hipStream_t stream) {
    const float* x = (const float*)d_in[0];   // [2048]
    const float* W = (const float*)d_in[1];   // [15, 2048, 2048]
    const float* b = (const float*)d_in[2];   // [15, 2048]
    float* out = (float*)d_out;               // [2048]

    float* v0 = (float*)d_ws;
    float* v1 = v0 + NN;

    const float* cur = x;
    for (int l = 0; l < NLAYERS; ++l) {
        float* dst = (l == NLAYERS - 1) ? out : ((l & 1) ? v1 : v0);
        layer_matvec<<<dim3(NN / 4), dim3(256), 0, stream>>>(
            W + (size_t)l * NN * NN, b + (size_t)l * NN, cur, dst,
            (l < NLAYERS - 1) ? 1 : 0);
        cur = dst;
    }
}